// Round 2
// baseline (1703.839 us; speedup 1.0000x reference)
//
#include <hip/hip_runtime.h>
#include <hip/hip_cooperative_groups.h>

namespace cg = cooperative_groups;

#define BATCH    1024
#define NUM_VARS 2048
#define LEAVES   (2 * NUM_VARS)              // 4096
#define LEVELS   12
#define WIDTH    4096
#define FANIN    4
#define TOTAL    (LEAVES + LEVELS * WIDTH)   // 53248

#define NBLK 1024   // 4 blocks/CU x 256 CUs -> exactly co-resident
#define NTHR 256

// ===========================================================================
// Fused cooperative kernel: leaf transpose + 12 levels + output copy.
// buf layout: [node][batch], batch contiguous (stride BATCH).
// ===========================================================================
__global__ __launch_bounds__(NTHR, 4)
void circuit_fused(const float* __restrict__ x,
                   const int4* __restrict__ child4,
                   const int*  __restrict__ op_type,
                   float* __restrict__ buf,
                   float* __restrict__ out)
{
    cg::grid_group grid = cg::this_grid();
    const int tid = threadIdx.x;
    const int blk = blockIdx.x;

    // ---- Phase 1: leaf materialization with LDS-tiled transpose ----------
    // 512 tiles of 64(v) x 64(b); blocks 0..511 active.
    __shared__ float tile[64][65];            // +1 pad: conflict-free both ways
    if (blk < 512) {
        const int v0 = (blk & 31) * 64;       // 32 v-tiles
        const int bb = (blk >> 5) * 64;       // 16 b-tiles
        const int tx = tid & 63;
        const int ty = tid >> 6;              // 0..3
        #pragma unroll
        for (int j = 0; j < 16; ++j) {
            const int bl = ty * 16 + j;
            // coalesced in tx (v is fast dim of x)
            tile[tx][bl] = x[(size_t)(bb + bl) * NUM_VARS + v0 + tx];
        }
        __syncthreads();
        #pragma unroll
        for (int j = 0; j < 16; ++j) {
            const int vl = ty * 16 + j;
            const float val = tile[vl][tx];
            // coalesced in tx (batch is fast dim of buf)
            buf[(size_t)(v0 + vl) * BATCH + bb + tx]            = val;
            buf[(size_t)(v0 + vl + NUM_VARS) * BATCH + bb + tx] = 1.0f - val;
        }
    }

    // ---- Phase 2: levels, grid-synced -----------------------------------
    for (int l = 0; l < LEVELS; ++l) {
        grid.sync();                          // leaf->L0 and Ll-1 -> Ll
        const int4* child = child4 + (size_t)l * WIDTH;
        const int*  op    = op_type + (size_t)l * WIDTH;
        float* outb = buf + (size_t)(LEAVES + l * WIDTH) * BATCH;
        #pragma unroll
        for (int i = 0; i < 4; ++i) {
            const int node = blk + i * NBLK;  // 4 nodes per block per level
            const int4 c = child[node];       // wave-uniform -> scalar loads
            const int  o = op[node];
            const float4 a0 = ((const float4*)(buf + (size_t)c.x * BATCH))[tid];
            const float4 a1 = ((const float4*)(buf + (size_t)c.y * BATCH))[tid];
            const float4 a2 = ((const float4*)(buf + (size_t)c.z * BATCH))[tid];
            const float4 a3 = ((const float4*)(buf + (size_t)c.w * BATCH))[tid];
            float4 r;
            if (o == 0) {  // AND: left-to-right product (matches np.prod)
                r.x = ((a0.x * a1.x) * a2.x) * a3.x;
                r.y = ((a0.y * a1.y) * a2.y) * a3.y;
                r.z = ((a0.z * a1.z) * a2.z) * a3.z;
                r.w = ((a0.w * a1.w) * a2.w) * a3.w;
            } else {       // OR: left-to-right sum
                r.x = ((a0.x + a1.x) + a2.x) + a3.x;
                r.y = ((a0.y + a1.y) + a2.y) + a3.y;
                r.z = ((a0.z + a1.z) + a2.z) + a3.z;
                r.w = ((a0.w + a1.w) + a2.w) + a3.w;
            }
            ((float4*)(outb + (size_t)node * BATCH))[tid] = r;
        }
    }

    // ---- Phase 3: root row -> out ---------------------------------------
    grid.sync();
    if (blk == 0) {
        ((float4*)out)[tid] =
            ((const float4*)(buf + (size_t)(TOTAL - 1) * BATCH))[tid];
    }
}

// ===========================================================================
// Fallback path (round-1 structure) in case cooperative launch fails.
// ===========================================================================
__global__ __launch_bounds__(1024) void leaf_kernel(const float* __restrict__ x,
                                                    float* __restrict__ buf)
{
    __shared__ float tile[64][65];
    const int v0 = blockIdx.x * 64;
    const int bb = blockIdx.y * 64;
    const int tv = threadIdx.x;
    const int tb = threadIdx.y;
    #pragma unroll
    for (int i = 0; i < 4; ++i) {
        const int bl = tb + i * 16;
        tile[tv][bl] = x[(size_t)(bb + bl) * NUM_VARS + v0 + tv];
    }
    __syncthreads();
    const int wb = threadIdx.x;
    #pragma unroll
    for (int i = 0; i < 4; ++i) {
        const int vl = tb + i * 16;
        const float val = tile[vl][wb];
        buf[(size_t)(v0 + vl) * BATCH + bb + wb]            = val;
        buf[(size_t)(v0 + vl + NUM_VARS) * BATCH + bb + wb] = 1.0f - val;
    }
}

__global__ __launch_bounds__(256) void level_kernel(const float* __restrict__ buf,
                                                    float* __restrict__ out_base,
                                                    const int4* __restrict__ child,
                                                    const int* __restrict__ op)
{
    const int w = blockIdx.x;
    const int4 c = child[w];
    const int  o = op[w];
    const int  t = threadIdx.x;
    const float4 a0 = ((const float4*)(buf + (size_t)c.x * BATCH))[t];
    const float4 a1 = ((const float4*)(buf + (size_t)c.y * BATCH))[t];
    const float4 a2 = ((const float4*)(buf + (size_t)c.z * BATCH))[t];
    const float4 a3 = ((const float4*)(buf + (size_t)c.w * BATCH))[t];
    float4 r;
    if (o == 0) {
        r.x = ((a0.x * a1.x) * a2.x) * a3.x;
        r.y = ((a0.y * a1.y) * a2.y) * a3.y;
        r.z = ((a0.z * a1.z) * a2.z) * a3.z;
        r.w = ((a0.w * a1.w) * a2.w) * a3.w;
    } else {
        r.x = ((a0.x + a1.x) + a2.x) + a3.x;
        r.y = ((a0.y + a1.y) + a2.y) + a3.y;
        r.z = ((a0.z + a1.z) + a2.z) + a3.z;
        r.w = ((a0.w + a1.w) + a2.w) + a3.w;
    }
    ((float4*)(out_base + (size_t)w * BATCH))[t] = r;
}

__global__ void out_kernel(const float* __restrict__ buf, float* __restrict__ out)
{
    const int t = blockIdx.x * blockDim.x + threadIdx.x;
    if (t < BATCH) out[t] = buf[(size_t)(TOTAL - 1) * BATCH + t];
}

extern "C" void kernel_launch(void* const* d_in, const int* in_sizes, int n_in,
                              void* d_out, int out_size, void* d_ws, size_t ws_size,
                              hipStream_t stream)
{
    const float* x      = (const float*)d_in[0];
    const int4*  child4 = (const int4*)d_in[1];
    const int*   op     = (const int*)d_in[2];
    float*       out    = (float*)d_out;
    float*       buf    = (float*)d_ws;

    void* args[] = {(void*)&x, (void*)&child4, (void*)&op, (void*)&buf, (void*)&out};
    hipError_t err = hipLaunchCooperativeKernel((const void*)circuit_fused,
                                                dim3(NBLK), dim3(NTHR),
                                                args, 0, stream);
    if (err != hipSuccess) {
        // Fallback: per-level kernels (round-1 structure, full batch).
        {
            dim3 blk(64, 16);
            dim3 grd(NUM_VARS / 64, BATCH / 64);
            leaf_kernel<<<grd, blk, 0, stream>>>(x, buf);
        }
        for (int l = 0; l < LEVELS; ++l) {
            const int4* child = child4 + (size_t)l * WIDTH;
            const int*  opl   = op + (size_t)l * WIDTH;
            float* out_base   = buf + (size_t)(LEAVES + l * WIDTH) * BATCH;
            level_kernel<<<WIDTH, BATCH / 4, 0, stream>>>(buf, out_base, child, opl);
        }
        out_kernel<<<(BATCH + 255) / 256, 256, 0, stream>>>(buf, out);
    }
}

// Round 3
// 231.855 us; speedup vs baseline: 7.3487x; 7.3487x over previous
//
#include <hip/hip_runtime.h>

#define BATCH    1024
#define NUM_VARS 2048
#define LEAVES   (2 * NUM_VARS)              // 4096
#define LEVELS   12
#define WIDTH    4096
#define FANIN    4
#define BC       512                          // batch chunk (2 chunks)

// ---------------------------------------------------------------------------
// Transpose x[1024][2048] -> xT[2048][1024] (8 MB). Leaves are NOT
// materialized: value(c) = xT[c][b] for c<NV, 1-xT[c-NV][b] for NV<=c<LEAVES.
// ---------------------------------------------------------------------------
__global__ __launch_bounds__(1024) void transpose_kernel(const float* __restrict__ x,
                                                         float* __restrict__ xT)
{
    __shared__ float tile[64][65];
    const int v0 = blockIdx.x * 64;           // 32 v-tiles
    const int bb = blockIdx.y * 64;           // 16 b-tiles
    const int tv = threadIdx.x;               // 0..63
    const int tb = threadIdx.y;               // 0..15
    #pragma unroll
    for (int i = 0; i < 4; ++i) {
        const int bl = tb + i * 16;
        tile[tv][bl] = x[(size_t)(bb + bl) * NUM_VARS + v0 + tv];   // coalesced in tv
    }
    __syncthreads();
    const int wb = threadIdx.x;
    #pragma unroll
    for (int i = 0; i < 4; ++i) {
        const int vl = tb + i * 16;
        xT[(size_t)(v0 + vl) * BATCH + bb + wb] = tile[vl][wb];      // coalesced in wb
    }
}

// ---------------------------------------------------------------------------
// Child-row gather: 3-way wave-uniform region select.
// xT rows are BATCH-wide (offset by b0); buf rows are BC-wide (chunk-local).
// ---------------------------------------------------------------------------
__device__ __forceinline__ float4 child_row(const float* __restrict__ xT,
                                            const float* __restrict__ buf,
                                            int c, int b0, int t)
{
    if (c < NUM_VARS) {
        return ((const float4*)(xT + (size_t)c * BATCH + b0))[t];
    } else if (c < LEAVES) {
        float4 v = ((const float4*)(xT + (size_t)(c - NUM_VARS) * BATCH + b0))[t];
        return make_float4(1.0f - v.x, 1.0f - v.y, 1.0f - v.z, 1.0f - v.w);
    } else {
        return ((const float4*)(buf + (size_t)(c - LEAVES) * BC))[t];
    }
}

// ---------------------------------------------------------------------------
// One level, one batch chunk. 2 nodes per 256-thread block (node is
// wave-uniform: waves 0-1 -> node0, waves 2-3 -> node1). Each of the 128
// threads per node covers a float4 of the BC-wide row.
// root_out != nullptr only on the last level: node WIDTH-1 is the circuit
// root; its threads also write d_out[b0 .. b0+BC).
// ---------------------------------------------------------------------------
__global__ __launch_bounds__(256) void level_kernel(const float* __restrict__ xT,
                                                    const float* __restrict__ buf,
                                                    float* __restrict__ out_base,
                                                    const int4* __restrict__ child,
                                                    const int*  __restrict__ op,
                                                    int b0,
                                                    float* __restrict__ root_out)
{
    const int local = threadIdx.x >> 7;       // 0..1
    const int t     = threadIdx.x & 127;      // float4 index into BC
    const int w     = blockIdx.x * 2 + local;

    const int4 c = child[w];                  // wave-uniform
    const int  o = op[w];

    const float4 a0 = child_row(xT, buf, c.x, b0, t);
    const float4 a1 = child_row(xT, buf, c.y, b0, t);
    const float4 a2 = child_row(xT, buf, c.z, b0, t);
    const float4 a3 = child_row(xT, buf, c.w, b0, t);

    float4 r;
    if (o == 0) {   // AND: left-to-right product (matches np.prod order)
        r.x = ((a0.x * a1.x) * a2.x) * a3.x;
        r.y = ((a0.y * a1.y) * a2.y) * a3.y;
        r.z = ((a0.z * a1.z) * a2.z) * a3.z;
        r.w = ((a0.w * a1.w) * a2.w) * a3.w;
    } else {        // OR: left-to-right sum
        r.x = ((a0.x + a1.x) + a2.x) + a3.x;
        r.y = ((a0.y + a1.y) + a2.y) + a3.y;
        r.z = ((a0.z + a1.z) + a2.z) + a3.z;
        r.w = ((a0.w + a1.w) + a2.w) + a3.w;
    }
    ((float4*)(out_base + (size_t)w * BC))[t] = r;

    if (root_out != nullptr && w == WIDTH - 1) {
        ((float4*)(root_out + b0))[t] = r;    // root node row -> d_out chunk
    }
}

extern "C" void kernel_launch(void* const* d_in, const int* in_sizes, int n_in,
                              void* d_out, int out_size, void* d_ws, size_t ws_size,
                              hipStream_t stream)
{
    const float* x         = (const float*)d_in[0];
    const int4*  child4    = (const int4*)d_in[1];
    const int*   op_type   = (const int*)d_in[2];
    float*       out       = (float*)d_out;

    // ws layout: [xT: 2048*1024 f32 = 8 MB][buf: 49152*512 f32 = 96 MB]
    float* xT  = (float*)d_ws;
    float* buf = xT + (size_t)NUM_VARS * BATCH;

    {
        dim3 blk(64, 16);
        dim3 grd(NUM_VARS / 64, BATCH / 64);
        transpose_kernel<<<grd, blk, 0, stream>>>(x, xT);
    }

    for (int b0 = 0; b0 < BATCH; b0 += BC) {          // 2 chunks, same buf region
        for (int l = 0; l < LEVELS; ++l) {
            const int4* child = child4 + (size_t)l * WIDTH;
            const int*  op    = op_type + (size_t)l * WIDTH;
            float* out_base   = buf + (size_t)l * WIDTH * BC;
            float* root_out   = (l == LEVELS - 1) ? out : nullptr;
            level_kernel<<<WIDTH / 2, 256, 0, stream>>>(xT, buf, out_base,
                                                        child, op, b0, root_out);
        }
    }
}

// Round 4
// 212.010 us; speedup vs baseline: 8.0366x; 1.0936x over previous
//
#include <hip/hip_runtime.h>

#define BATCH    1024
#define NUM_VARS 2048
#define LEAVES   (2 * NUM_VARS)              // 4096
#define LEVELS   12
#define WIDTH    4096

// ---------------------------------------------------------------------------
// Transpose x[1024][2048] -> xT[2048][1024] (8 MB). Leaves stay implicit:
//   value(c) = xT[c][b]                for c < NUM_VARS
//   value(c) = 1 - xT[c-NUM_VARS][b]   for NUM_VARS <= c < LEAVES
// ---------------------------------------------------------------------------
__global__ __launch_bounds__(1024) void transpose_kernel(const float* __restrict__ x,
                                                         float* __restrict__ xT)
{
    __shared__ float tile[64][65];
    const int v0 = blockIdx.x * 64;           // 32 v-tiles
    const int bb = blockIdx.y * 64;           // 16 b-tiles
    const int tv = threadIdx.x;               // 0..63
    const int tb = threadIdx.y;               // 0..15
    #pragma unroll
    for (int i = 0; i < 4; ++i) {
        const int bl = tb + i * 16;
        tile[tv][bl] = x[(size_t)(bb + bl) * NUM_VARS + v0 + tv];   // coalesced in tv
    }
    __syncthreads();
    const int wb = threadIdx.x;
    #pragma unroll
    for (int i = 0; i < 4; ++i) {
        const int vl = tb + i * 16;
        xT[(size_t)(v0 + vl) * BATCH + bb + wb] = tile[vl][wb];      // coalesced in wb
    }
}

// Branch-free (uniform) child row pointer: leaves fold to xT via c & 2047,
// internal nodes to buf. The 1-x fixup is applied after the load so all
// loads issue unconditionally (deep VMEM pipeline).
__device__ __forceinline__ const float4* child_ptr(const float* __restrict__ xT,
                                                   const float* __restrict__ buf,
                                                   int c)
{
    const float* p = (c < LEAVES)
        ? xT  + (size_t)(c & (NUM_VARS - 1)) * BATCH
        : buf + (size_t)(c - LEAVES) * BATCH;
    return (const float4*)p;
}

__device__ __forceinline__ float4 fixup(float4 v, int c)
{
    if (c >= NUM_VARS && c < LEAVES) {        // uniform; complement literal
        v.x = 1.0f - v.x; v.y = 1.0f - v.y; v.z = 1.0f - v.z; v.w = 1.0f - v.w;
    }
    return v;
}

__device__ __forceinline__ float4 combine(float4 a0, float4 a1, float4 a2, float4 a3, int o)
{
    float4 r;
    if (o == 0) {   // AND: left-to-right product (np.prod order)
        r.x = ((a0.x * a1.x) * a2.x) * a3.x;
        r.y = ((a0.y * a1.y) * a2.y) * a3.y;
        r.z = ((a0.z * a1.z) * a2.z) * a3.z;
        r.w = ((a0.w * a1.w) * a2.w) * a3.w;
    } else {        // OR: left-to-right sum
        r.x = ((a0.x + a1.x) + a2.x) + a3.x;
        r.y = ((a0.y + a1.y) + a2.y) + a3.y;
        r.z = ((a0.z + a1.z) + a2.z) + a3.z;
        r.w = ((a0.w + a1.w) + a2.w) + a3.w;
    }
    return r;
}

// ---------------------------------------------------------------------------
// One level, full batch. 2 nodes per 256-thread block; thread t owns float4
// column t for BOTH nodes -> 8 independent coalesced loads in flight.
// Grid = WIDTH/2 = 2048 blocks.
// ---------------------------------------------------------------------------
__global__ __launch_bounds__(256) void level_kernel(const float* __restrict__ xT,
                                                    const float* __restrict__ buf,
                                                    float* __restrict__ out_base,
                                                    const int4* __restrict__ child,
                                                    const int*  __restrict__ op,
                                                    float* __restrict__ root_out)
{
    const int t  = threadIdx.x;               // float4 index into 1024-wide row
    const int w0 = blockIdx.x * 2;
    const int w1 = w0 + 1;

    const int4 c0 = child[w0];                // wave-uniform -> scalar loads
    const int4 c1 = child[w1];
    const int  o0 = op[w0];
    const int  o1 = op[w1];

    // Issue all 8 loads unconditionally.
    float4 a0 = child_ptr(xT, buf, c0.x)[t];
    float4 a1 = child_ptr(xT, buf, c0.y)[t];
    float4 a2 = child_ptr(xT, buf, c0.z)[t];
    float4 a3 = child_ptr(xT, buf, c0.w)[t];
    float4 b0 = child_ptr(xT, buf, c1.x)[t];
    float4 b1 = child_ptr(xT, buf, c1.y)[t];
    float4 b2 = child_ptr(xT, buf, c1.z)[t];
    float4 b3 = child_ptr(xT, buf, c1.w)[t];

    a0 = fixup(a0, c0.x); a1 = fixup(a1, c0.y); a2 = fixup(a2, c0.z); a3 = fixup(a3, c0.w);
    b0 = fixup(b0, c1.x); b1 = fixup(b1, c1.y); b2 = fixup(b2, c1.z); b3 = fixup(b3, c1.w);

    const float4 r0 = combine(a0, a1, a2, a3, o0);
    const float4 r1 = combine(b0, b1, b2, b3, o1);

    ((float4*)(out_base + (size_t)w0 * BATCH))[t] = r0;
    ((float4*)(out_base + (size_t)w1 * BATCH))[t] = r1;

    if (root_out != nullptr && w1 == WIDTH - 1) {
        ((float4*)root_out)[t] = r1;          // root row -> d_out (folded copy)
    }
}

extern "C" void kernel_launch(void* const* d_in, const int* in_sizes, int n_in,
                              void* d_out, int out_size, void* d_ws, size_t ws_size,
                              hipStream_t stream)
{
    const float* x       = (const float*)d_in[0];
    const int4*  child4  = (const int4*)d_in[1];
    const int*   op_type = (const int*)d_in[2];
    float*       out     = (float*)d_out;

    // ws layout: [xT: 2048*1024 f32 = 8 MB][buf: 49152 rows * 4 KB = 192 MB]
    float* xT  = (float*)d_ws;
    float* buf = xT + (size_t)NUM_VARS * BATCH;

    {
        dim3 blk(64, 16);
        dim3 grd(NUM_VARS / 64, BATCH / 64);
        transpose_kernel<<<grd, blk, 0, stream>>>(x, xT);
    }

    for (int l = 0; l < LEVELS; ++l) {
        const int4* child = child4 + (size_t)l * WIDTH;
        const int*  op    = op_type + (size_t)l * WIDTH;
        float* out_base   = buf + (size_t)l * WIDTH * BATCH;
        float* root_out   = (l == LEVELS - 1) ? out : nullptr;
        level_kernel<<<WIDTH / 2, 256, 0, stream>>>(xT, buf, out_base,
                                                    child, op, root_out);
    }
}